// Round 1
// baseline (1863.768 us; speedup 1.0000x reference)
//
#include <hip/hip_runtime.h>

typedef unsigned short u16;
typedef unsigned int   u32;
typedef u16   u16x8 __attribute__((ext_vector_type(8)));
typedef __bf16 bf16x8 __attribute__((ext_vector_type(8)));
typedef float f32x4 __attribute__((ext_vector_type(4)));
typedef float f32x4v __attribute__((ext_vector_type(4)));

#define N_NODES 4096
#define N_EDGES 16384
#define SEQ 8
#define DIM 512
#define NLAYER 2
#define NROWS_X (N_NODES*SEQ)     /* 32768 */
#define NROWS_E (N_EDGES*SEQ)     /* 131072 */

__device__ __forceinline__ float b2f(u16 u){ return __uint_as_float(((u32)u)<<16); }
__device__ __forceinline__ u16 f2b(float f){ u32 b=__float_as_uint(f); b += 0x7FFFu + ((b>>16)&1u); return (u16)(b>>16); }

// ---------------- weight transpose + norm-w fold: dst[N][K] = src[K][N] * fold[K] ----------------
__global__ void k_tf(const float* __restrict__ src, u16* __restrict__ dst,
                     const float* __restrict__ fold, int K, int N)
{
    int idx = blockIdx.x * 256 + threadIdx.x;
    if (idx >= K * N) return;
    int c = idx / N, j = idx - c * N;
    float v = src[idx];
    if (fold) v *= fold[c];
    dst[(size_t)j * K + c] = f2b(v);
}

// ---------------- rope tables: cos/sin[l*64+d], angle = l * theta^(-2(d&31)/64) ----------------
__global__ void k_rope(float* __restrict__ cosT, float* __restrict__ sinT)
{
    int t = threadIdx.x;              // 512 threads
    int l = t >> 6, d = t & 63, i = d & 31;
    float freq = expf(-(2.0f * i / 64.0f) * logf(10000.0f));
    float ang = l * freq;
    cosT[t] = cosf(ang);
    sinT[t] = sinf(ang);
}

// ---------------- per-row: sumsq -> scale, write raw bf16 copy (wave per row) ----------------
__global__ void k_rowprep(const float* __restrict__ src, u16* __restrict__ dst,
                          float* __restrict__ scale)
{
    int row  = blockIdx.x * 4 + (threadIdx.x >> 6);
    int lane = threadIdx.x & 63;
    const float* p = src + (size_t)row * DIM;
    f32x4v v0 = *(const f32x4v*)(p + lane * 8);
    f32x4v v1 = *(const f32x4v*)(p + lane * 8 + 4);
    float ss = v0[0]*v0[0]+v0[1]*v0[1]+v0[2]*v0[2]+v0[3]*v0[3]
             + v1[0]*v1[0]+v1[1]*v1[1]+v1[2]*v1[2]+v1[3]*v1[3];
    #pragma unroll
    for (int d = 1; d < 64; d <<= 1) ss += __shfl_xor(ss, d);
    if (lane == 0) scale[row] = rsqrtf(ss / (float)DIM + 1e-6f);
    u16x8 o;
    #pragma unroll
    for (int i = 0; i < 4; ++i) o[i] = f2b(v0[i]);
    #pragma unroll
    for (int i = 0; i < 4; ++i) o[4+i] = f2b(v1[i]);
    *(u16x8*)(dst + (size_t)row * DIM + lane * 8) = o;
}

// ---------------- edge rows: gather h[N+emap[e]] slice l, sumsq -> s_xe, bf16 copy (once) -----
__global__ void k_edgeprep(const float* __restrict__ hidden, const int* __restrict__ emap,
                           u16* __restrict__ dst, float* __restrict__ scale)
{
    int er   = blockIdx.x * 4 + (threadIdx.x >> 6);   // 0..131071
    int lane = threadIdx.x & 63;
    int e = er >> 3, l = er & 7;
    const float* p = hidden + ((size_t)(N_NODES + emap[e]) * SEQ + l) * DIM;
    f32x4v v0 = *(const f32x4v*)(p + lane * 8);
    f32x4v v1 = *(const f32x4v*)(p + lane * 8 + 4);
    float ss = v0[0]*v0[0]+v0[1]*v0[1]+v0[2]*v0[2]+v0[3]*v0[3]
             + v1[0]*v1[0]+v1[1]*v1[1]+v1[2]*v1[2]+v1[3]*v1[3];
    #pragma unroll
    for (int d = 1; d < 64; d <<= 1) ss += __shfl_xor(ss, d);
    if (lane == 0) scale[er] = rsqrtf(ss / (float)DIM + 1e-6f);
    u16x8 o;
    #pragma unroll
    for (int i = 0; i < 4; ++i) o[i] = f2b(v0[i]);
    #pragma unroll
    for (int i = 0; i < 4; ++i) o[4+i] = f2b(v1[i]);
    *(u16x8*)(dst + (size_t)er * DIM + lane * 8) = o;
}

// ---------------- CSR build ----------------
__global__ void k_count(const int* __restrict__ dstA, int* __restrict__ cnt)
{
    int e = blockIdx.x * 256 + threadIdx.x;
    if (e < N_EDGES) atomicAdd(&cnt[dstA[e]], 1);
}
__global__ void k_scan(const int* __restrict__ cnt, int* __restrict__ off)
{
    __shared__ int part[256];
    int t = threadIdx.x;
    int base = t * 16;
    int loc[16]; int s = 0;
    #pragma unroll
    for (int i = 0; i < 16; ++i) { loc[i] = s; s += cnt[base + i]; }
    part[t] = s; __syncthreads();
    for (int d = 1; d < 256; d <<= 1) {
        int v = (t >= d) ? part[t - d] : 0;
        __syncthreads();
        part[t] += v;
        __syncthreads();
    }
    int pre = (t == 0) ? 0 : part[t - 1];
    #pragma unroll
    for (int i = 0; i < 16; ++i) off[base + i] = pre + loc[i];
    if (t == 255) off[N_NODES] = part[255];
}
__global__ void k_fill(const int* __restrict__ dstA, const int* __restrict__ off,
                       int* __restrict__ cur, int* __restrict__ elist)
{
    int e = blockIdx.x * 256 + threadIdx.x;
    if (e < N_EDGES) {
        int d = dstA[e];
        int pos = off[d] + atomicAdd(&cur[d], 1);
        elist[pos] = e;
    }
}

// ---------------- bf16 MFMA GEMM: C[M,N] = rowscale .* (A[M,K] @ Bt[N,K]^T) + bias (+relu) + residual
// 128x128 tile, BK=32, 4 waves of 64x64, reg-staged double-buffered LDS, XOR chunk swizzle.
__global__ __launch_bounds__(256, 2) void k_gemm(
    const u16* __restrict__ A, const u16* __restrict__ B,
    int M, int N, int K,
    const float* __restrict__ rowscale, const float* __restrict__ bias,
    int relu, const float* __restrict__ residual,
    float* __restrict__ outF, u16* __restrict__ outH)
{
    __shared__ u16 ldsA[2][128 * 32];
    __shared__ u16 ldsB[2][128 * 32];
    int tid  = threadIdx.x;
    int lane = tid & 63, wid = tid >> 6;
    int row0 = blockIdx.x * 128, col0 = blockIdx.y * 128;

    // staging: thread owns LDS chunk slots p0=tid, p1=tid+256 (chunk = 16B = 8 bf16)
    int p0 = tid, p1 = tid + 256;
    int r0 = p0 >> 2, c0 = p0 & 3;
    int r1 = p1 >> 2, c1 = p1 & 3;
    int cg0 = c0 ^ ((r0 & 3) ^ ((r0 >> 2) & 3));
    int cg1 = c1 ^ ((r1 & 3) ^ ((r1 >> 2) & 3));
    const u16* pa0 = A + (size_t)(row0 + r0) * K + cg0 * 8;
    const u16* pa1 = A + (size_t)(row0 + r1) * K + cg1 * 8;
    const u16* pb0 = B + (size_t)(col0 + r0) * K + cg0 * 8;
    const u16* pb1 = B + (size_t)(col0 + r1) * K + cg1 * 8;

    int NT = K / 32;
    u16x8 ra0, ra1, rb0, rb1;
    auto loadT = [&](int kt) {
        int ko = kt * 32;
        ra0 = *(const u16x8*)(pa0 + ko);
        ra1 = *(const u16x8*)(pa1 + ko);
        rb0 = *(const u16x8*)(pb0 + ko);
        rb1 = *(const u16x8*)(pb1 + ko);
    };
    auto writeT = [&](int b) {
        *(u16x8*)&ldsA[b][p0 * 8] = ra0;
        *(u16x8*)&ldsA[b][p1 * 8] = ra1;
        *(u16x8*)&ldsB[b][p0 * 8] = rb0;
        *(u16x8*)&ldsB[b][p1 * 8] = rb1;
    };

    f32x4 acc[4][4];
    #pragma unroll
    for (int m = 0; m < 4; ++m)
        #pragma unroll
        for (int n = 0; n < 4; ++n) { f32x4 z = {0.f,0.f,0.f,0.f}; acc[m][n] = z; }

    int wr = wid >> 1, wc = wid & 1;
    int g = lane >> 4;
    int swz = (lane & 3) ^ ((lane >> 2) & 3);
    int cread = g ^ swz;
    int arow_l = wr * 64 + (lane & 15);
    int brow_l = wc * 64 + (lane & 15);

    loadT(0); writeT(0);
    if (NT > 1) loadT(1);
    __syncthreads();
    int cur = 0;
    for (int kt = 0; kt < NT; ++kt) {
        bf16x8 af[4], bfr[4];
        #pragma unroll
        for (int m = 0; m < 4; ++m)
            af[m] = *(const bf16x8*)&ldsA[cur][((arow_l + m * 16) * 4 + cread) * 8];
        #pragma unroll
        for (int n = 0; n < 4; ++n)
            bfr[n] = *(const bf16x8*)&ldsB[cur][((brow_l + n * 16) * 4 + cread) * 8];
        #pragma unroll
        for (int m = 0; m < 4; ++m)
            #pragma unroll
            for (int n = 0; n < 4; ++n)
                acc[m][n] = __builtin_amdgcn_mfma_f32_16x16x32_bf16(af[m], bfr[n], acc[m][n], 0, 0, 0);
        if (kt + 1 < NT) {
            writeT(cur ^ 1);
            if (kt + 2 < NT) loadT(kt + 2);
        }
        __syncthreads();
        cur ^= 1;
    }

    // epilogue: C row = row0 + wr*64 + m*16 + g*4 + j ; col = col0 + wc*64 + n*16 + (lane&15)
    #pragma unroll
    for (int m = 0; m < 4; ++m) {
        int rbase = row0 + wr * 64 + m * 16 + g * 4;
        #pragma unroll
        for (int n = 0; n < 4; ++n) {
            int col = col0 + wc * 64 + n * 16 + (lane & 15);
            #pragma unroll
            for (int j = 0; j < 4; ++j) {
                int row = rbase + j;
                float v = acc[m][n][j];
                if (rowscale) v *= rowscale[row];
                if (bias)     v += bias[col];
                if (relu)     v = fmaxf(v, 0.f);
                if (residual) v += residual[(size_t)row * N + col];
                if (outF) outF[(size_t)row * N + col] = v;
                else      outH[(size_t)row * N + col] = f2b(v);
            }
        }
    }
}

// ---------------- per-node attention: online segment softmax + aggregate ----------------
// block = node; 256 thr = 64 (l,head) pairs x 4 lanes x 16 dims
__global__ __launch_bounds__(256, 2) void k_attn(
    const u16* __restrict__ qkv, const u16* __restrict__ ekv,
    const int* __restrict__ srcA, const int* __restrict__ off,
    const int* __restrict__ elist,
    const float* __restrict__ cosT, const float* __restrict__ sinT,
    u16* __restrict__ agg)
{
    int n = blockIdx.x;
    int t = threadIdx.x;
    int pair = t >> 2, sub = t & 3;
    int l = pair >> 3, hd = pair & 7;
    int d0 = sub * 16;
    int dp = (sub ^ 2) * 16;
    float sgn = (sub < 2) ? -1.f : 1.f;

    const float* cosL = cosT + l * 64;
    const float* sinL = sinT + l * 64;

    size_t qrow = ((size_t)n * SEQ + l) * 1536;
    float qi[16];
    {
        u16x8 qa = *(const u16x8*)&qkv[qrow + hd * 64 + d0];
        u16x8 qb = *(const u16x8*)&qkv[qrow + hd * 64 + d0 + 8];
        u16x8 pa = *(const u16x8*)&qkv[qrow + hd * 64 + dp];
        u16x8 pb = *(const u16x8*)&qkv[qrow + hd * 64 + dp + 8];
        #pragma unroll
        for (int i = 0; i < 8; ++i) {
            qi[i]     = b2f(qa[i]) * cosL[d0 + i]     + sgn * b2f(pa[i]) * sinL[d0 + i];
            qi[i + 8] = b2f(qb[i]) * cosL[d0 + i + 8] + sgn * b2f(pb[i]) * sinL[d0 + i + 8];
        }
    }

    float mrun = -INFINITY, s = 0.f;
    float av[16];
    #pragma unroll
    for (int i = 0; i < 16; ++i) av[i] = 0.f;

    int e0 = off[n], e1 = off[n + 1];
    for (int ii = e0; ii < e1; ++ii) {
        int e = elist[ii];
        int es = srcA[e];
        size_t krow = ((size_t)es * SEQ + l) * 1536 + 512;
        size_t vrow = krow + 512;
        size_t erow = ((size_t)e * SEQ + l) * 1024;

        u16x8 ka  = *(const u16x8*)&qkv[krow + hd * 64 + d0];
        u16x8 kb  = *(const u16x8*)&qkv[krow + hd * 64 + d0 + 8];
        u16x8 kpa = *(const u16x8*)&qkv[krow + hd * 64 + dp];
        u16x8 kpb = *(const u16x8*)&qkv[krow + hd * 64 + dp + 8];
        u16x8 ea  = *(const u16x8*)&ekv[erow + hd * 64 + d0];
        u16x8 eb  = *(const u16x8*)&ekv[erow + hd * 64 + d0 + 8];
        u16x8 epa = *(const u16x8*)&ekv[erow + hd * 64 + dp];
        u16x8 epb = *(const u16x8*)&ekv[erow + hd * 64 + dp + 8];

        float dot = 0.f;
        #pragma unroll
        for (int i = 0; i < 8; ++i) {
            float ko = b2f(ka[i]) + b2f(ea[i]);
            float kp = b2f(kpa[i]) + b2f(epa[i]);
            float kj = ko * cosL[d0 + i] + sgn * kp * sinL[d0 + i];
            dot += qi[i] * kj;
            float ko2 = b2f(kb[i]) + b2f(eb[i]);
            float kp2 = b2f(kpb[i]) + b2f(epb[i]);
            float kj2 = ko2 * cosL[d0 + i + 8] + sgn * kp2 * sinL[d0 + i + 8];
            dot += qi[i + 8] * kj2;
        }
        dot += __shfl_xor(dot, 1);
        dot += __shfl_xor(dot, 2);
        float alpha = dot * 0.125f;     // 1/sqrt(64)

        float mn = fmaxf(mrun, alpha);
        float f = expf(mrun - mn);      // mrun=-inf -> 0
        float p = expf(alpha - mn);
        s = s * f + p;

        u16x8 va  = *(const u16x8*)&qkv[vrow + hd * 64 + d0];
        u16x8 vb  = *(const u16x8*)&qkv[vrow + hd * 64 + d0 + 8];
        u16x8 eva = *(const u16x8*)&ekv[erow + 512 + hd * 64 + d0];
        u16x8 evb = *(const u16x8*)&ekv[erow + 512 + hd * 64 + d0 + 8];
        #pragma unroll
        for (int i = 0; i < 8; ++i) {
            av[i]     = av[i]     * f + p * (b2f(va[i]) + b2f(eva[i]));
            av[i + 8] = av[i + 8] * f + p * (b2f(vb[i]) + b2f(evb[i]));
        }
        mrun = mn;
    }

    float inv = 1.f / (s + 1e-16f);
    size_t orow = ((size_t)n * SEQ + l) * DIM + hd * 64 + d0;
    #pragma unroll
    for (int i = 0; i < 16; ++i) agg[orow + i] = f2b(av[i] * inv);
}

extern "C" void kernel_launch(void* const* d_in, const int* in_sizes, int n_in,
                              void* d_out, int out_size, void* d_ws, size_t ws_size,
                              hipStream_t stream)
{
    const float* hidden = (const float*)d_in[0];
    const int*   eidx   = (const int*)d_in[1];
    const int*   srcA   = eidx;              // edge_index[0]
    const int*   dstA   = eidx + N_EDGES;    // edge_index[1]
    const int*   emap   = (const int*)d_in[2];
    const float* W_qkv  = (const float*)d_in[4];
    const float* W_e    = (const float*)d_in[5];
    const float* W_o    = (const float*)d_in[6];
    const float* xw     = (const float*)d_in[7];
    const float* xew    = (const float*)d_in[8];
    const float* pw     = (const float*)d_in[9];
    const float* W1     = (const float*)d_in[10];
    const float* b1     = (const float*)d_in[11];
    const float* W2     = (const float*)d_in[12];
    const float* b2     = (const float*)d_in[13];

    char* w = (char*)d_ws;
    auto alloc = [&](size_t bytes) { char* p = w; w += (bytes + 255) & ~(size_t)255; return p; };
    u16*  WtQKV  = (u16*)alloc((size_t)NLAYER * 1536 * 512 * 2);
    u16*  WtE    = (u16*)alloc((size_t)NLAYER * 1024 * 512 * 2);
    u16*  WtO    = (u16*)alloc((size_t)NLAYER * 512 * 512 * 2);
    u16*  Wt1    = (u16*)alloc((size_t)NLAYER * 1024 * 512 * 2);
    u16*  Wt2    = (u16*)alloc((size_t)NLAYER * 512 * 1024 * 2);
    float* cosT  = (float*)alloc(512 * 4);
    float* sinT  = (float*)alloc(512 * 4);
    float* s_x   = (float*)alloc((size_t)NROWS_X * 4);
    float* s_xe  = (float*)alloc((size_t)NROWS_E * 4);
    float* s_post= (float*)alloc((size_t)NROWS_X * 4);
    int*  cnt    = (int*)alloc((N_NODES + 1) * 4);
    int*  off    = (int*)alloc((N_NODES + 1) * 4);
    int*  cur    = (int*)alloc(N_NODES * 4);
    int*  elist  = (int*)alloc(N_EDGES * 4);
    float* h_nodes = (float*)alloc((size_t)NROWS_X * DIM * 4);
    u16*  hn_bf  = (u16*)alloc((size_t)NROWS_X * DIM * 2);
    u16*  he_bf  = (u16*)alloc((size_t)NROWS_E * DIM * 2);
    u16*  qkv    = (u16*)alloc((size_t)NROWS_X * 1536 * 2);
    u16*  aggB   = (u16*)alloc((size_t)NROWS_X * DIM * 2);
    float* out_buf = (float*)alloc((size_t)NROWS_X * DIM * 4);
    u16*  o_bf   = (u16*)alloc((size_t)NROWS_X * DIM * 2);
    u16*  ffmid  = (u16*)alloc((size_t)NROWS_X * 1024 * 2);
    // ekv scratch lives in d_out's edge region (exact size match: 131072*1024*2B = 16384*4096*4B)
    u16*  ekv    = (u16*)((float*)d_out + (size_t)NROWS_X * DIM);

    // ---- one-time prep ----
    hipMemcpyAsync(h_nodes, hidden, (size_t)NROWS_X * DIM * 4, hipMemcpyDeviceToDevice, stream);
    k_rope<<<1, 512, 0, stream>>>(cosT, sinT);
    for (int l = 0; l < NLAYER; ++l) {
        k_tf<<<(512*1536 + 255)/256, 256, 0, stream>>>(W_qkv + (size_t)l*512*1536, WtQKV + (size_t)l*1536*512, xw  + l*512, 512, 1536);
        k_tf<<<(512*1024 + 255)/256, 256, 0, stream>>>(W_e   + (size_t)l*512*1024, WtE   + (size_t)l*1024*512, xew + l*512, 512, 1024);
        k_tf<<<(512*512  + 255)/256, 256, 0, stream>>>(W_o   + (size_t)l*512*512,  WtO   + (size_t)l*512*512,  nullptr,    512, 512);
        k_tf<<<(512*1024 + 255)/256, 256, 0, stream>>>(W1    + (size_t)l*512*1024, Wt1   + (size_t)l*1024*512, pw  + l*512, 512, 1024);
        k_tf<<<(1024*512 + 255)/256, 256, 0, stream>>>(W2    + (size_t)l*1024*512, Wt2   + (size_t)l*512*1024, nullptr,    1024, 512);
    }
    k_edgeprep<<<NROWS_E/4, 256, 0, stream>>>(hidden, emap, he_bf, s_xe);
    hipMemsetAsync(cnt, 0, (N_NODES + 1) * 4, stream);
    hipMemsetAsync(cur, 0, N_NODES * 4, stream);
    k_count<<<N_EDGES/256, 256, 0, stream>>>(dstA, cnt);
    k_scan<<<1, 256, 0, stream>>>(cnt, off);
    k_fill<<<N_EDGES/256, 256, 0, stream>>>(dstA, off, cur, elist);

    // ---- layers ----
    for (int l = 0; l < NLAYER; ++l) {
        k_rowprep<<<NROWS_X/4, 256, 0, stream>>>(h_nodes, hn_bf, s_x);
        dim3 g1(NROWS_X/128, 1536/128);
        k_gemm<<<g1, 256, 0, stream>>>(hn_bf, WtQKV + (size_t)l*1536*512, NROWS_X, 1536, 512,
                                       s_x, nullptr, 0, nullptr, nullptr, qkv);
        dim3 g2(NROWS_E/128, 1024/128);
        k_gemm<<<g2, 256, 0, stream>>>(he_bf, WtE + (size_t)l*1024*512, NROWS_E, 1024, 512,
                                       s_xe, nullptr, 0, nullptr, nullptr, ekv);
        k_attn<<<N_NODES, 256, 0, stream>>>(qkv, ekv, srcA, off, elist, cosT, sinT, aggB);
        dim3 g3(NROWS_X/128, 512/128);
        k_gemm<<<g3, 256, 0, stream>>>(aggB, WtO + (size_t)l*512*512, NROWS_X, 512, 512,
                                       nullptr, nullptr, 0, h_nodes, out_buf, nullptr);
        k_rowprep<<<NROWS_X/4, 256, 0, stream>>>(out_buf, o_bf, s_post);
        dim3 g4(NROWS_X/128, 1024/128);
        k_gemm<<<g4, 256, 0, stream>>>(o_bf, Wt1 + (size_t)l*1024*512, NROWS_X, 1024, 512,
                                       s_post, b1 + l*1024, 1, nullptr, nullptr, ffmid);
        dim3 g5(NROWS_X/128, 512/128);
        k_gemm<<<g5, 256, 0, stream>>>(ffmid, Wt2 + (size_t)l*512*1024, NROWS_X, 512, 1024,
                                       nullptr, b2 + l*512, 0, out_buf, h_nodes, nullptr);
    }

    // ---- final output assembly (edge-region copy also overwrites ekv scratch) ----
    hipMemcpyAsync(d_out, h_nodes, (size_t)NROWS_X * DIM * 4, hipMemcpyDeviceToDevice, stream);
    hipMemcpyAsync((float*)d_out + (size_t)NROWS_X * DIM, hidden + (size_t)NROWS_X * DIM,
                   (size_t)N_EDGES * SEQ * DIM * 4, hipMemcpyDeviceToDevice, stream);
}

// Round 2
// 1768.495 us; speedup vs baseline: 1.0539x; 1.0539x over previous
//
#include <hip/hip_runtime.h>

typedef unsigned short u16;
typedef unsigned int   u32;
typedef u16   u16x8 __attribute__((ext_vector_type(8)));
typedef __bf16 bf16x8 __attribute__((ext_vector_type(8)));
typedef float f32x4 __attribute__((ext_vector_type(4)));
typedef float f32x4v __attribute__((ext_vector_type(4)));

#define N_NODES 4096
#define N_EDGES 16384
#define SEQ 8
#define DIM 512
#define NLAYER 2
#define NROWS_X (N_NODES*SEQ)     /* 32768 */
#define NROWS_E (N_EDGES*SEQ)     /* 131072 */

__device__ __forceinline__ float b2f(u16 u){ return __uint_as_float(((u32)u)<<16); }
__device__ __forceinline__ u16 f2b(float f){ u32 b=__float_as_uint(f); b += 0x7FFFu + ((b>>16)&1u); return (u16)(b>>16); }

__device__ __forceinline__ void gl16(const u16* g, u16* l) {
    __builtin_amdgcn_global_load_lds((const __attribute__((address_space(1))) void*)g,
                                     (__attribute__((address_space(3))) void*)l, 16, 0, 0);
}

// ---------------- weight transpose + norm-w fold: dst[N][K] = src[K][N] * fold[K] ----------------
__global__ void k_tf(const float* __restrict__ src, u16* __restrict__ dst,
                     const float* __restrict__ fold, int K, int N)
{
    int idx = blockIdx.x * 256 + threadIdx.x;
    if (idx >= K * N) return;
    int c = idx / N, j = idx - c * N;
    float v = src[idx];
    if (fold) v *= fold[c];
    dst[(size_t)j * K + c] = f2b(v);
}

// ---------------- per-row: sumsq -> scale, write raw bf16 copy (wave per row) ----------------
__global__ void k_rowprep(const float* __restrict__ src, u16* __restrict__ dst,
                          float* __restrict__ scale)
{
    int row  = blockIdx.x * 4 + (threadIdx.x >> 6);
    int lane = threadIdx.x & 63;
    const float* p = src + (size_t)row * DIM;
    f32x4v v0 = *(const f32x4v*)(p + lane * 8);
    f32x4v v1 = *(const f32x4v*)(p + lane * 8 + 4);
    float ss = v0[0]*v0[0]+v0[1]*v0[1]+v0[2]*v0[2]+v0[3]*v0[3]
             + v1[0]*v1[0]+v1[1]*v1[1]+v1[2]*v1[2]+v1[3]*v1[3];
    #pragma unroll
    for (int d = 1; d < 64; d <<= 1) ss += __shfl_xor(ss, d);
    if (lane == 0) scale[row] = rsqrtf(ss / (float)DIM + 1e-6f);
    u16x8 o;
    #pragma unroll
    for (int i = 0; i < 4; ++i) o[i] = f2b(v0[i]);
    #pragma unroll
    for (int i = 0; i < 4; ++i) o[4+i] = f2b(v1[i]);
    *(u16x8*)(dst + (size_t)row * DIM + lane * 8) = o;
}

// ---------------- edge rows: gather h[N+emap[e]] slice l, sumsq -> s_xe, bf16 copy (once) -----
__global__ void k_edgeprep(const float* __restrict__ hidden, const int* __restrict__ emap,
                           u16* __restrict__ dst, float* __restrict__ scale)
{
    int er   = blockIdx.x * 4 + (threadIdx.x >> 6);   // 0..131071
    int lane = threadIdx.x & 63;
    int e = er >> 3, l = er & 7;
    const float* p = hidden + ((size_t)(N_NODES + emap[e]) * SEQ + l) * DIM;
    f32x4v v0 = *(const f32x4v*)(p + lane * 8);
    f32x4v v1 = *(const f32x4v*)(p + lane * 8 + 4);
    float ss = v0[0]*v0[0]+v0[1]*v0[1]+v0[2]*v0[2]+v0[3]*v0[3]
             + v1[0]*v1[0]+v1[1]*v1[1]+v1[2]*v1[2]+v1[3]*v1[3];
    #pragma unroll
    for (int d = 1; d < 64; d <<= 1) ss += __shfl_xor(ss, d);
    if (lane == 0) scale[er] = rsqrtf(ss / (float)DIM + 1e-6f);
    u16x8 o;
    #pragma unroll
    for (int i = 0; i < 4; ++i) o[i] = f2b(v0[i]);
    #pragma unroll
    for (int i = 0; i < 4; ++i) o[4+i] = f2b(v1[i]);
    *(u16x8*)(dst + (size_t)er * DIM + lane * 8) = o;
}

// ---------------- CSR build ----------------
__global__ void k_count(const int* __restrict__ dstA, int* __restrict__ cnt)
{
    int e = blockIdx.x * 256 + threadIdx.x;
    if (e < N_EDGES) atomicAdd(&cnt[dstA[e]], 1);
}
__global__ void k_scan(const int* __restrict__ cnt, int* __restrict__ off)
{
    __shared__ int part[256];
    int t = threadIdx.x;
    int base = t * 16;
    int loc[16]; int s = 0;
    #pragma unroll
    for (int i = 0; i < 16; ++i) { loc[i] = s; s += cnt[base + i]; }
    part[t] = s; __syncthreads();
    for (int d = 1; d < 256; d <<= 1) {
        int v = (t >= d) ? part[t - d] : 0;
        __syncthreads();
        part[t] += v;
        __syncthreads();
    }
    int pre = (t == 0) ? 0 : part[t - 1];
    #pragma unroll
    for (int i = 0; i < 16; ++i) off[base + i] = pre + loc[i];
    if (t == 255) off[N_NODES] = part[255];
}
__global__ void k_fill(const int* __restrict__ dstA, const int* __restrict__ off,
                       int* __restrict__ cur, int* __restrict__ elist)
{
    int e = blockIdx.x * 256 + threadIdx.x;
    if (e < N_EDGES) {
        int d = dstA[e];
        int pos = off[d] + atomicAdd(&cur[d], 1);
        elist[pos] = e;
    }
}

// ---------------- bf16 MFMA GEMM (m97 structure): C[M,N] = rowscale.*(A@Bt^T)+bias(+relu)+residual
// 128x128 tile, BK=32, 4 waves of 64x64, global_load_lds w=16 staging, linear LDS, dbuf.
// 1-D grid, gx = N/128 fastest (A-panel reuse), chunked XCD swizzle (nwg%8==0 required).
__global__ __launch_bounds__(256, 2) void k_gemm(
    const u16* __restrict__ A, const u16* __restrict__ B,
    int M, int N, int K, int gx,
    const float* __restrict__ rowscale, const float* __restrict__ bias,
    int relu, const float* __restrict__ residual,
    float* __restrict__ outF, u16* __restrict__ outH)
{
    __shared__ u16 ldsA[2][128 * 32];
    __shared__ u16 ldsB[2][128 * 32];
    int tid  = threadIdx.x;
    int lane = tid & 63, wid = tid >> 6;

    // chunked XCD swizzle: XCD x owns a contiguous wgid range (nwg % 8 == 0)
    int nwg  = gridDim.x;
    int q    = nwg >> 3;
    int wgid = (blockIdx.x & 7) * q + (blockIdx.x >> 3);
    int colt = wgid % gx, rowt = wgid / gx;
    int row0 = rowt * 128, col0 = colt * 128;

    // staging geometry: wave w issues 2 A-loads + 2 B-loads per K-tile,
    // each load: 64 lanes x 16B -> 1KB linear LDS (16 rows of 32 bf16)
    const u16* ga0 = A + (size_t)(row0 + wid * 32 + (lane >> 2)) * K + (lane & 3) * 8;
    const u16* ga1 = ga0 + (size_t)16 * K;
    const u16* gb0 = B + (size_t)(col0 + wid * 32 + (lane >> 2)) * K + (lane & 3) * 8;
    const u16* gb1 = gb0 + (size_t)16 * K;

    auto stage = [&](int buf, int kt) {
        int ko = kt * 32;
        gl16(ga0 + ko, &ldsA[buf][wid * 1024]);
        gl16(ga1 + ko, &ldsA[buf][wid * 1024 + 512]);
        gl16(gb0 + ko, &ldsB[buf][wid * 1024]);
        gl16(gb1 + ko, &ldsB[buf][wid * 1024 + 512]);
    };

    f32x4 acc[4][4];
    #pragma unroll
    for (int m = 0; m < 4; ++m)
        #pragma unroll
        for (int n = 0; n < 4; ++n) { f32x4 z = {0.f,0.f,0.f,0.f}; acc[m][n] = z; }

    int wr = wid >> 1, wc = wid & 1;
    int m15 = lane & 15, g = lane >> 4;
    int arow_l = wr * 64 + m15;
    int brow_l = wc * 64 + m15;

    int NT = K / 32;
    stage(0, 0);
    int cur = 0;
    for (int kt = 0; kt < NT; ++kt) {
        __syncthreads();                        // drains vmcnt: buf[cur] ready, prev reads done
        if (kt + 1 < NT) stage(cur ^ 1, kt + 1);
        bf16x8 af[4], bfr[4];
        #pragma unroll
        for (int m = 0; m < 4; ++m)
            af[m] = *(const bf16x8*)&ldsA[cur][(arow_l + m * 16) * 32 + g * 8];
        #pragma unroll
        for (int n = 0; n < 4; ++n)
            bfr[n] = *(const bf16x8*)&ldsB[cur][(brow_l + n * 16) * 32 + g * 8];
        #pragma unroll
        for (int m = 0; m < 4; ++m)
            #pragma unroll
            for (int n = 0; n < 4; ++n)
                acc[m][n] = __builtin_amdgcn_mfma_f32_16x16x32_bf16(af[m], bfr[n], acc[m][n], 0, 0, 0);
        cur ^= 1;
    }

    // epilogue: C row = row0 + wr*64 + m*16 + g*4 + j ; col = col0 + wc*64 + n*16 + (lane&15)
    #pragma unroll
    for (int m = 0; m < 4; ++m) {
        int rbase = row0 + wr * 64 + m * 16 + g * 4;
        #pragma unroll
        for (int n = 0; n < 4; ++n) {
            int col = col0 + wc * 64 + n * 16 + m15;
            #pragma unroll
            for (int j = 0; j < 4; ++j) {
                int row = rbase + j;
                float v = acc[m][n][j];
                if (rowscale) v *= rowscale[row];
                if (bias)     v += bias[col];
                if (relu)     v = fmaxf(v, 0.f);
                if (residual) v += residual[(size_t)row * N + col];
                if (outF) outF[(size_t)row * N + col] = v;
                else      outH[(size_t)row * N + col] = f2b(v);
            }
        }
    }
}

// ---------------- per-node attention: online segment softmax + aggregate (RoPE eliminated:
// both sides rotated by the same position l -> orthogonal rotation cancels in the dot) ------
__global__ __launch_bounds__(256, 2) void k_attn(
    const u16* __restrict__ qkv, const u16* __restrict__ ekv,
    const int* __restrict__ srcA, const int* __restrict__ off,
    const int* __restrict__ elist,
    u16* __restrict__ agg)
{
    int n = blockIdx.x;
    int t = threadIdx.x;
    int pair = t >> 2, sub = t & 3;
    int l = pair >> 3, hd = pair & 7;
    int doff = hd * 64 + sub * 16;

    size_t qrow = ((size_t)n * SEQ + l) * 1536;
    float qi[16];
    {
        u16x8 qa = *(const u16x8*)&qkv[qrow + doff];
        u16x8 qb = *(const u16x8*)&qkv[qrow + doff + 8];
        #pragma unroll
        for (int i = 0; i < 8; ++i) { qi[i] = b2f(qa[i]); qi[i + 8] = b2f(qb[i]); }
    }

    float mrun = -INFINITY, s = 0.f;
    float av[16];
    #pragma unroll
    for (int i = 0; i < 16; ++i) av[i] = 0.f;

    int e0 = off[n], e1 = off[n + 1];
    for (int ii = e0; ii < e1; ++ii) {
        int e = elist[ii];
        int es = srcA[e];
        size_t krow = ((size_t)es * SEQ + l) * 1536 + 512;
        size_t erow = ((size_t)e * SEQ + l) * 1024;

        u16x8 ka = *(const u16x8*)&qkv[krow + doff];
        u16x8 kb = *(const u16x8*)&qkv[krow + doff + 8];
        u16x8 ea = *(const u16x8*)&ekv[erow + doff];
        u16x8 eb = *(const u16x8*)&ekv[erow + doff + 8];

        float dot = 0.f;
        #pragma unroll
        for (int i = 0; i < 8; ++i) {
            dot += qi[i]     * (b2f(ka[i]) + b2f(ea[i]));
            dot += qi[i + 8] * (b2f(kb[i]) + b2f(eb[i]));
        }
        dot += __shfl_xor(dot, 1);
        dot += __shfl_xor(dot, 2);
        float alpha = dot * 0.125f;     // 1/sqrt(64)

        float mn = fmaxf(mrun, alpha);
        float f = expf(mrun - mn);      // mrun=-inf -> 0
        float p = expf(alpha - mn);
        s = s * f + p;

        u16x8 va  = *(const u16x8*)&qkv[krow + 512 + doff];
        u16x8 vb  = *(const u16x8*)&qkv[krow + 512 + doff + 8];
        u16x8 eva = *(const u16x8*)&ekv[erow + 512 + doff];
        u16x8 evb = *(const u16x8*)&ekv[erow + 512 + doff + 8];
        #pragma unroll
        for (int i = 0; i < 8; ++i) {
            av[i]     = av[i]     * f + p * (b2f(va[i]) + b2f(eva[i]));
            av[i + 8] = av[i + 8] * f + p * (b2f(vb[i]) + b2f(evb[i]));
        }
        mrun = mn;
    }

    float inv = 1.f / (s + 1e-16f);
    size_t orow = ((size_t)n * SEQ + l) * DIM + doff;
    #pragma unroll
    for (int i = 0; i < 16; ++i) agg[orow + i] = f2b(av[i] * inv);
}

extern "C" void kernel_launch(void* const* d_in, const int* in_sizes, int n_in,
                              void* d_out, int out_size, void* d_ws, size_t ws_size,
                              hipStream_t stream)
{
    const float* hidden = (const float*)d_in[0];
    const int*   eidx   = (const int*)d_in[1];
    const int*   srcA   = eidx;              // edge_index[0]
    const int*   dstA   = eidx + N_EDGES;    // edge_index[1]
    const int*   emap   = (const int*)d_in[2];
    const float* W_qkv  = (const float*)d_in[4];
    const float* W_e    = (const float*)d_in[5];
    const float* W_o    = (const float*)d_in[6];
    const float* xw     = (const float*)d_in[7];
    const float* xew    = (const float*)d_in[8];
    const float* pw     = (const float*)d_in[9];
    const float* W1     = (const float*)d_in[10];
    const float* b1     = (const float*)d_in[11];
    const float* W2     = (const float*)d_in[12];
    const float* b2     = (const float*)d_in[13];

    char* w = (char*)d_ws;
    auto alloc = [&](size_t bytes) { char* p = w; w += (bytes + 255) & ~(size_t)255; return p; };
    u16*  WtQKV  = (u16*)alloc((size_t)NLAYER * 1536 * 512 * 2);
    u16*  WtE    = (u16*)alloc((size_t)NLAYER * 1024 * 512 * 2);
    u16*  WtO    = (u16*)alloc((size_t)NLAYER * 512 * 512 * 2);
    u16*  Wt1    = (u16*)alloc((size_t)NLAYER * 1024 * 512 * 2);
    u16*  Wt2    = (u16*)alloc((size_t)NLAYER * 512 * 1024 * 2);
    float* s_x   = (float*)alloc((size_t)NROWS_X * 4);
    float* s_xe  = (float*)alloc((size_t)NROWS_E * 4);
    float* s_post= (float*)alloc((size_t)NROWS_X * 4);
    int*  cnt    = (int*)alloc((N_NODES + 1) * 4);
    int*  off    = (int*)alloc((N_NODES + 1) * 4);
    int*  cur    = (int*)alloc(N_NODES * 4);
    int*  elist  = (int*)alloc(N_EDGES * 4);
    float* h_nodes = (float*)alloc((size_t)NROWS_X * DIM * 4);
    u16*  hn_bf  = (u16*)alloc((size_t)NROWS_X * DIM * 2);
    u16*  he_bf  = (u16*)alloc((size_t)NROWS_E * DIM * 2);
    u16*  qkv    = (u16*)alloc((size_t)NROWS_X * 1536 * 2);
    u16*  aggB   = (u16*)alloc((size_t)NROWS_X * DIM * 2);
    float* out_buf = (float*)alloc((size_t)NROWS_X * DIM * 4);
    u16*  o_bf   = (u16*)alloc((size_t)NROWS_X * DIM * 2);
    u16*  ffmid  = (u16*)alloc((size_t)NROWS_X * 1024 * 2);
    // ekv scratch lives in d_out's edge region (exact size match: 131072*1024*2B = 16384*4096*4B)
    u16*  ekv    = (u16*)((float*)d_out + (size_t)NROWS_X * DIM);

    // ---- one-time prep ----
    hipMemcpyAsync(h_nodes, hidden, (size_t)NROWS_X * DIM * 4, hipMemcpyDeviceToDevice, stream);
    for (int l = 0; l < NLAYER; ++l) {
        k_tf<<<(512*1536 + 255)/256, 256, 0, stream>>>(W_qkv + (size_t)l*512*1536, WtQKV + (size_t)l*1536*512, xw  + l*512, 512, 1536);
        k_tf<<<(512*1024 + 255)/256, 256, 0, stream>>>(W_e   + (size_t)l*512*1024, WtE   + (size_t)l*1024*512, xew + l*512, 512, 1024);
        k_tf<<<(512*512  + 255)/256, 256, 0, stream>>>(W_o   + (size_t)l*512*512,  WtO   + (size_t)l*512*512,  nullptr,    512, 512);
        k_tf<<<(512*1024 + 255)/256, 256, 0, stream>>>(W1    + (size_t)l*512*1024, Wt1   + (size_t)l*1024*512, pw  + l*512, 512, 1024);
        k_tf<<<(1024*512 + 255)/256, 256, 0, stream>>>(W2    + (size_t)l*1024*512, Wt2   + (size_t)l*512*1024, nullptr,    1024, 512);
    }
    k_edgeprep<<<NROWS_E/4, 256, 0, stream>>>(hidden, emap, he_bf, s_xe);
    hipMemsetAsync(cnt, 0, (N_NODES + 1) * 4, stream);
    hipMemsetAsync(cur, 0, N_NODES * 4, stream);
    k_count<<<N_EDGES/256, 256, 0, stream>>>(dstA, cnt);
    k_scan<<<1, 256, 0, stream>>>(cnt, off);
    k_fill<<<N_EDGES/256, 256, 0, stream>>>(dstA, off, cur, elist);

    // ---- layers ----
    for (int l = 0; l < NLAYER; ++l) {
        int last = (l == NLAYER - 1);
        k_rowprep<<<NROWS_X/4, 256, 0, stream>>>(h_nodes, hn_bf, s_x);
        k_gemm<<<(NROWS_X/128)*(1536/128), 256, 0, stream>>>(hn_bf, WtQKV + (size_t)l*1536*512,
            NROWS_X, 1536, 512, 1536/128, s_x, nullptr, 0, nullptr, nullptr, qkv);
        k_gemm<<<(NROWS_E/128)*(1024/128), 256, 0, stream>>>(he_bf, WtE + (size_t)l*1024*512,
            NROWS_E, 1024, 512, 1024/128, s_xe, nullptr, 0, nullptr, nullptr, ekv);
        k_attn<<<N_NODES, 256, 0, stream>>>(qkv, ekv, srcA, off, elist, aggB);
        k_gemm<<<(NROWS_X/128)*(512/128), 256, 0, stream>>>(aggB, WtO + (size_t)l*512*512,
            NROWS_X, 512, 512, 512/128, nullptr, nullptr, 0, h_nodes, out_buf, nullptr);
        k_rowprep<<<NROWS_X/4, 256, 0, stream>>>(out_buf, o_bf, s_post);
        k_gemm<<<(NROWS_X/128)*(1024/128), 256, 0, stream>>>(o_bf, Wt1 + (size_t)l*1024*512,
            NROWS_X, 1024, 512, 1024/128, s_post, b1 + l*1024, 1, nullptr, nullptr, ffmid);
        k_gemm<<<(NROWS_X/128)*(512/128), 256, 0, stream>>>(ffmid, Wt2 + (size_t)l*512*1024,
            NROWS_X, 512, 1024, 512/128, nullptr, b2 + l*512, 0, out_buf,
            last ? (float*)d_out : h_nodes, nullptr);
    }

    // ---- edge-region copy (also overwrites ekv scratch; node region written by last FF2) ----
    hipMemcpyAsync((float*)d_out + (size_t)NROWS_X * DIM, hidden + (size_t)NROWS_X * DIM,
                   (size_t)N_EDGES * SEQ * DIM * 4, hipMemcpyDeviceToDevice, stream);
}